// Round 1
// baseline (49.776 us; speedup 1.0000x reference)
//
#include <hip/hip_runtime.h>

// Problem constants
#define N_NODES 4096
#define IN_DIM  512
#define REPR    512
#define NH      8
#define KD      64
#define HID     2048
#define LN_EPS  1e-5f

// Workspace float offsets
#define OFF_PART 0              // 256 floats: node-sum partials
#define OFF_CV   256            // 512 floats: cv[h*64+m] = sum_k Wvs[h,k,m]
#define OFF_S    768            // 1 float: grand sum of node_matrix
#define OFF_TH   1024           // 8*512: per-head partial t
#define OFF_XHAT 5120           // 512: LN1 output
#define OFF_H1   5632           // 2048: FFN hidden
#define OFF_YP   7680           // 16*512: FFN2 partials
#define OFF_ROW  15872          // 512: final row

// K1: node-matrix partial sums (blocks 0..255) + cv (blocks 256..263)
__global__ void k1_partials_cv(const float* __restrict__ node,
                               const float* __restrict__ Wvs,
                               float* __restrict__ ws) {
    const int bid = blockIdx.x, t = threadIdx.x;
    __shared__ float sm[256];
    if (bid < 256) {
        const float4* n4 = (const float4*)node;   // 524288 float4 total
        float acc = 0.f;
        const int base = bid * 2048;
        #pragma unroll
        for (int i = 0; i < 8; ++i) {
            float4 v = n4[base + i * 256 + t];
            acc += v.x + v.y + v.z + v.w;
        }
        sm[t] = acc;
        __syncthreads();
        for (int s = 128; s > 0; s >>= 1) {
            if (t < s) sm[t] += sm[t + s];
            __syncthreads();
        }
        if (t == 0) ws[OFF_PART + bid] = sm[0];
    } else {
        const int h = bid - 256;
        const int n = t & 63, ks = t >> 6;
        float acc = 0.f;
        for (int k = ks; k < IN_DIM; k += 4)
            acc += Wvs[h * (IN_DIM * KD) + k * KD + n];
        sm[t] = acc;
        __syncthreads();
        if (ks == 0)
            ws[OFF_CV + h * KD + n] = sm[n] + sm[64 + n] + sm[128 + n] + sm[192 + n];
    }
}

// K2: per-head t partials (blocks 0..7) + finalize S (block 8)
__global__ void k2_t_and_s(const float* __restrict__ Wo, float* __restrict__ ws) {
    const int bid = blockIdx.x, t = threadIdx.x;  // 512 threads
    if (bid < 8) {
        __shared__ float cvs[64];
        if (t < 64) cvs[t] = ws[OFF_CV + bid * 64 + t];
        __syncthreads();
        float acc = 0.f;
        const float* wo = Wo + bid * KD * REPR;
        #pragma unroll 8
        for (int m = 0; m < KD; ++m)
            acc += cvs[m] * wo[m * REPR + t];
        ws[OFF_TH + bid * REPR + t] = acc;
    } else {
        __shared__ float sm[256];
        if (t < 256) sm[t] = ws[OFF_PART + t];
        __syncthreads();
        for (int s = 128; s > 0; s >>= 1) {
            if (t < s) sm[t] += sm[t + s];
            __syncthreads();
        }
        if (t == 0) ws[OFF_S] = sm[0];
    }
}

// K3: combine t, scale by S, LayerNorm1 -> xhat
__global__ void k3_ln1(const float* __restrict__ g1, const float* __restrict__ be1,
                       float* __restrict__ ws) {
    const int n = threadIdx.x;  // 512
    __shared__ float sm[512];
    __shared__ float s_mu, s_inv;
    float tn = 0.f;
    #pragma unroll
    for (int h = 0; h < NH; ++h) tn += ws[OFF_TH + h * REPR + n];
    const float r = ws[OFF_S] * tn;
    sm[n] = r; __syncthreads();
    for (int s = 256; s > 0; s >>= 1) { if (n < s) sm[n] += sm[n + s]; __syncthreads(); }
    if (n == 0) s_mu = sm[0] * (1.f / REPR);
    __syncthreads();
    const float d = r - s_mu;
    sm[n] = d * d; __syncthreads();
    for (int s = 256; s > 0; s >>= 1) { if (n < s) sm[n] += sm[n + s]; __syncthreads(); }
    if (n == 0) s_inv = rsqrtf(sm[0] * (1.f / REPR) + LN_EPS);
    __syncthreads();
    ws[OFF_XHAT + n] = d * s_inv * g1[n] + be1[n];
}

// K4: FFN layer 1 (xhat @ W1 + b1, relu) — 8 blocks x 256 threads
__global__ void k4_ffn1(const float* __restrict__ W1, const float* __restrict__ b1,
                        float* __restrict__ ws) {
    const int t = threadIdx.x;          // 256
    const int j = blockIdx.x * 256 + t; // 0..2047
    __shared__ float xs[512];
    xs[t] = ws[OFF_XHAT + t];
    xs[t + 256] = ws[OFF_XHAT + t + 256];
    __syncthreads();
    float acc = 0.f;
    #pragma unroll 8
    for (int n = 0; n < REPR; ++n)
        acc += xs[n] * W1[n * HID + j];
    const float v = acc + b1[j];
    ws[OFF_H1 + j] = v > 0.f ? v : 0.f;
}

// K5: FFN layer 2 partials — 16 blocks x 512 threads, each block a 128-chunk of j
__global__ void k5_ffn2(const float* __restrict__ W2, float* __restrict__ ws) {
    const int t = threadIdx.x;   // 512
    const int bid = blockIdx.x;  // 16
    __shared__ float hs[128];
    if (t < 128) hs[t] = ws[OFF_H1 + bid * 128 + t];
    __syncthreads();
    float acc = 0.f;
    const float* w = W2 + bid * 128 * REPR;
    #pragma unroll 8
    for (int j = 0; j < 128; ++j)
        acc += hs[j] * w[j * REPR + t];
    ws[OFF_YP + bid * REPR + t] = acc;
}

// K6: combine FFN2 partials + b2, LayerNorm2 -> row
__global__ void k6_ln2(const float* __restrict__ b2, const float* __restrict__ g2,
                       const float* __restrict__ be2, float* __restrict__ ws) {
    const int n = threadIdx.x;  // 512
    __shared__ float sm[512];
    __shared__ float s_mu, s_inv;
    float y = b2[n];
    #pragma unroll
    for (int b = 0; b < 16; ++b) y += ws[OFF_YP + b * REPR + n];
    sm[n] = y; __syncthreads();
    for (int s = 256; s > 0; s >>= 1) { if (n < s) sm[n] += sm[n + s]; __syncthreads(); }
    if (n == 0) s_mu = sm[0] * (1.f / REPR);
    __syncthreads();
    const float d = y - s_mu;
    sm[n] = d * d; __syncthreads();
    for (int s = 256; s > 0; s >>= 1) { if (n < s) sm[n] += sm[n + s]; __syncthreads(); }
    if (n == 0) s_inv = rsqrtf(sm[0] * (1.f / REPR) + LN_EPS);
    __syncthreads();
    ws[OFF_ROW + n] = d * s_inv * g2[n] + be2[n];
}

// K7: broadcast row to all 4096 output rows (float4 stores)
__global__ void k7_bcast(const float* __restrict__ ws, float* __restrict__ out) {
    const float4* row4 = (const float4*)(ws + OFF_ROW);  // 128 float4
    float4* o4 = (float4*)out;                           // 524288 float4
    const int g = blockIdx.x * blockDim.x + threadIdx.x; // 0..131071
    #pragma unroll
    for (int i = 0; i < 4; ++i) {
        const int idx = g + i * 131072;
        o4[idx] = row4[idx & 127];
    }
}

extern "C" void kernel_launch(void* const* d_in, const int* in_sizes, int n_in,
                              void* d_out, int out_size, void* d_ws, size_t ws_size,
                              hipStream_t stream) {
    const float* node = (const float*)d_in[0];
    // d_in[1] adjacency, d_in[2] Wks, d_in[3] Wqs — analytically unused
    const float* Wvs  = (const float*)d_in[4];
    const float* Wo   = (const float*)d_in[5];
    const float* W1   = (const float*)d_in[6];
    const float* b1   = (const float*)d_in[7];
    const float* W2   = (const float*)d_in[8];
    const float* b2   = (const float*)d_in[9];
    const float* g1   = (const float*)d_in[10];
    const float* be1  = (const float*)d_in[11];
    const float* g2   = (const float*)d_in[12];
    const float* be2  = (const float*)d_in[13];
    float* ws  = (float*)d_ws;
    float* out = (float*)d_out;

    k1_partials_cv<<<dim3(264), dim3(256), 0, stream>>>(node, Wvs, ws);
    k2_t_and_s   <<<dim3(9),   dim3(512), 0, stream>>>(Wo, ws);
    k3_ln1       <<<dim3(1),   dim3(512), 0, stream>>>(g1, be1, ws);
    k4_ffn1      <<<dim3(8),   dim3(256), 0, stream>>>(W1, b1, ws);
    k5_ffn2      <<<dim3(16),  dim3(512), 0, stream>>>(W2, ws);
    k6_ln2       <<<dim3(1),   dim3(512), 0, stream>>>(b2, g2, be2, ws);
    k7_bcast     <<<dim3(512), dim3(256), 0, stream>>>(ws, out);
}

// Round 2
// 24.293 us; speedup vs baseline: 2.0490x; 2.0490x over previous
//
#include <hip/hip_runtime.h>

#define NN   4096
#define IND  512
#define REPR 512
#define NH   8
#define KD   64
#define HID  2048
#define LN_EPS 1e-5f

// ws float offsets (all 16B-aligned)
#define OFF_NP   0        // 512   node partial sums
#define OFF_CVP  512      // 64*64 cv partials (8 heads x 8 k-chunks x 64)
#define OFF_S    4608     // 1     grand sum of node_matrix
#define OFF_THP  4864     // 32*512 t partials (8 heads x 4 m-chunks)
#define OFF_H1P  21248    // 16*2048 ffn1 partials (16 n-chunks)
#define OFF_YP   54016    // 32*512 ffn2 partials (32 j-chunks)
// total 70400 floats = 281.6 KB

__device__ inline float wave_reduce(float v) {
    #pragma unroll
    for (int o = 32; o > 0; o >>= 1) v += __shfl_xor(v, o);
    return v;
}

// block-wide sum for 256-thread blocks; sred must be float[4]
__device__ inline float block_reduce_256(float v, float* sred, int t) {
    v = wave_reduce(v);
    if ((t & 63) == 0) sred[t >> 6] = v;
    __syncthreads();
    float r = sred[0] + sred[1] + sred[2] + sred[3];
    __syncthreads();
    return r;
}

// K1: blocks 0..511 -> node partial sums; blocks 512..575 -> cv partials
__global__ void k1_sums(const float* __restrict__ node, const float* __restrict__ Wvs,
                        float* __restrict__ ws) {
    const int bid = blockIdx.x, t = threadIdx.x;  // 256 threads
    __shared__ float sred[8];
    __shared__ float sm[256];
    if (bid < 512) {
        const float4* n4 = (const float4*)node;   // 524288 float4
        const int base = bid * 1024;
        float acc = 0.f;
        #pragma unroll
        for (int i = 0; i < 4; ++i) {
            float4 v = n4[base + i * 256 + t];
            acc += (v.x + v.y) + (v.z + v.w);
        }
        acc = wave_reduce(acc);
        if ((t & 63) == 0) sred[t >> 6] = acc;
        __syncthreads();
        if (t == 0) ws[OFF_NP + bid] = sred[0] + sred[1] + sred[2] + sred[3];
    } else {
        const int b = bid - 512;            // 0..63
        const int h = b >> 3, c = b & 7;    // head, 64-wide k-chunk
        const int n = t & 63, ks = t >> 6;  // ks 0..3
        const float* w = Wvs + h * (IND * KD);
        float acc = 0.f;
        #pragma unroll
        for (int q = 0; q < 16; ++q) {
            const int k = c * 64 + ks + q * 4;
            acc += w[k * KD + n];
        }
        sm[t] = acc;
        __syncthreads();
        if (ks == 0)
            ws[OFF_CVP + b * 64 + n] = sm[n] + sm[64 + n] + sm[128 + n] + sm[192 + n];
    }
}

// K2: blocks 0..31 -> t partials (head h, m-chunk mc); block 32 -> finalize S
__global__ void k2_t_s(const float* __restrict__ Wo, float* __restrict__ ws) {
    const int bid = blockIdx.x, t = threadIdx.x;  // 512 threads
    __shared__ float cvs[64];
    __shared__ float sred[8];
    if (bid < 32) {
        const int h = bid >> 2, mc = bid & 3;
        if (t < 64) {
            float a = 0.f;
            #pragma unroll
            for (int c = 0; c < 8; ++c) a += ws[OFF_CVP + (h * 8 + c) * 64 + t];
            cvs[t] = a;
        }
        __syncthreads();
        const float* wo = Wo + h * (KD * REPR);
        float acc = 0.f;
        #pragma unroll
        for (int q = 0; q < 16; ++q) {
            const int m = mc * 16 + q;
            acc += cvs[m] * wo[m * REPR + t];
        }
        ws[OFF_THP + bid * REPR + t] = acc;
    } else {
        float v = wave_reduce(ws[OFF_NP + t]);
        if ((t & 63) == 0) sred[t >> 6] = v;
        __syncthreads();
        if (t == 0) {
            float s = 0.f;
            #pragma unroll
            for (int i = 0; i < 8; ++i) s += sred[i];
            ws[OFF_S] = s;
        }
    }
}

// K4: fused (combine t + scale S + LN1) redundant per block, then FFN1 partial.
// 32 blocks x 256 threads: jc = bid&1 (1024 j's via float4), nc = bid>>1 (32 n's)
__global__ void k4_ln1_ffn1(const float* __restrict__ g1, const float* __restrict__ be1,
                            const float* __restrict__ W1, float* __restrict__ ws) {
    const int bid = blockIdx.x, t = threadIdx.x;
    const int jc = bid & 1, nc = bid >> 1;
    __shared__ float xs[REPR];
    __shared__ float sred[4];
    const float S = ws[OFF_S];
    if (t < 128) {
        const float4* thp4 = (const float4*)(ws + OFF_THP);
        float4 a = make_float4(0.f, 0.f, 0.f, 0.f);
        #pragma unroll
        for (int b = 0; b < 32; ++b) {
            float4 v = thp4[b * 128 + t];
            a.x += v.x; a.y += v.y; a.z += v.z; a.w += v.w;
        }
        ((float4*)xs)[t] = make_float4(S * a.x, S * a.y, S * a.z, S * a.w);
    }
    __syncthreads();
    const float v0 = xs[t], v1 = xs[t + 256];
    const float tot = block_reduce_256(v0 + v1, sred, t);
    const float mu = tot * (1.f / REPR);
    const float d0 = v0 - mu, d1 = v1 - mu;
    const float var = block_reduce_256(d0 * d0 + d1 * d1, sred, t);
    const float inv = rsqrtf(var * (1.f / REPR) + LN_EPS);
    __syncthreads();
    xs[t]       = d0 * inv * g1[t] + be1[t];
    xs[t + 256] = d1 * inv * g1[t + 256] + be1[t + 256];
    __syncthreads();
    const float4* W14 = (const float4*)W1;  // row n = 512 float4
    float4 acc = make_float4(0.f, 0.f, 0.f, 0.f);
    #pragma unroll 8
    for (int q = 0; q < 32; ++q) {
        const int n = nc * 32 + q;
        const float x = xs[n];
        const float4 w = W14[n * 512 + jc * 256 + t];
        acc.x += x * w.x; acc.y += x * w.y; acc.z += x * w.z; acc.w += x * w.w;
    }
    // float offset = nc*2048 + jc*1024 + 4t  => h1p[nc][j], j = jc*1024 + 4t + comp
    ((float4*)(ws + OFF_H1P))[nc * 512 + jc * 256 + t] = acc;
}

// K5: h finalize (64 j's) + FFN2 partial. 32 blocks x 512 threads.
__global__ void k5_ffn2(const float* __restrict__ b1, const float* __restrict__ W2,
                        float* __restrict__ ws) {
    const int bid = blockIdx.x, t = threadIdx.x;
    __shared__ float hs[64];
    __shared__ float4 part[512];
    if (t < 64) {
        const int j = bid * 64 + t;
        float v = b1[j];
        #pragma unroll
        for (int nc = 0; nc < 16; ++nc) v += ws[OFF_H1P + nc * 2048 + j];
        hs[t] = v > 0.f ? v : 0.f;
    }
    __syncthreads();
    const int n4 = t & 127, jg = t >> 7;   // 4 j-groups of 16
    const float4* W24 = (const float4*)W2; // row j = 128 float4
    float4 acc = make_float4(0.f, 0.f, 0.f, 0.f);
    #pragma unroll 8
    for (int q = 0; q < 16; ++q) {
        const int jj = jg * 16 + q;
        const float hv = hs[jj];
        const float4 w = W24[(bid * 64 + jj) * 128 + n4];
        acc.x += hv * w.x; acc.y += hv * w.y; acc.z += hv * w.z; acc.w += hv * w.w;
    }
    part[t] = acc;
    __syncthreads();
    if (t < 128) {
        const float4 a = part[t], b = part[128 + t], c = part[256 + t], d = part[384 + t];
        ((float4*)(ws + OFF_YP))[bid * 128 + t] =
            make_float4(a.x + b.x + c.x + d.x, a.y + b.y + c.y + d.y,
                        a.z + b.z + c.z + d.z, a.w + b.w + c.w + d.w);
    }
}

// K6: fused (combine yp + b2 + LN2) redundant per block, then write 8 output rows.
// 512 blocks x 256 threads.
__global__ void k6_ln2_bcast(const float* __restrict__ b2, const float* __restrict__ g2,
                             const float* __restrict__ be2, const float* __restrict__ ws,
                             float* __restrict__ out) {
    const int bid = blockIdx.x, t = threadIdx.x;
    __shared__ float row[REPR];
    __shared__ float sred[4];
    if (t < 128) {
        const float4* yp4 = (const float4*)(ws + OFF_YP);
        float4 a = make_float4(0.f, 0.f, 0.f, 0.f);
        #pragma unroll
        for (int b = 0; b < 32; ++b) {
            float4 v = yp4[b * 128 + t];
            a.x += v.x; a.y += v.y; a.z += v.z; a.w += v.w;
        }
        const float4 bb = ((const float4*)b2)[t];
        ((float4*)row)[t] = make_float4(a.x + bb.x, a.y + bb.y, a.z + bb.z, a.w + bb.w);
    }
    __syncthreads();
    const float v0 = row[t], v1 = row[t + 256];
    const float tot = block_reduce_256(v0 + v1, sred, t);
    const float mu = tot * (1.f / REPR);
    const float d0 = v0 - mu, d1 = v1 - mu;
    const float var = block_reduce_256(d0 * d0 + d1 * d1, sred, t);
    const float inv = rsqrtf(var * (1.f / REPR) + LN_EPS);
    __syncthreads();
    row[t]       = d0 * inv * g2[t] + be2[t];
    row[t + 256] = d1 * inv * g2[t + 256] + be2[t + 256];
    __syncthreads();
    const float4* r4 = (const float4*)row;      // 128 float4
    float4* o4 = (float4*)out + bid * 1024;     // 8 rows per block
    #pragma unroll
    for (int i = 0; i < 4; ++i) {
        const int idx = i * 256 + t;
        o4[idx] = r4[idx & 127];
    }
}

extern "C" void kernel_launch(void* const* d_in, const int* in_sizes, int n_in,
                              void* d_out, int out_size, void* d_ws, size_t ws_size,
                              hipStream_t stream) {
    const float* node = (const float*)d_in[0];
    // d_in[1] adjacency, d_in[2] Wks, d_in[3] Wqs — analytically unused
    const float* Wvs  = (const float*)d_in[4];
    const float* Wo   = (const float*)d_in[5];
    const float* W1   = (const float*)d_in[6];
    const float* b1   = (const float*)d_in[7];
    const float* W2   = (const float*)d_in[8];
    const float* b2   = (const float*)d_in[9];
    const float* g1   = (const float*)d_in[10];
    const float* be1  = (const float*)d_in[11];
    const float* g2   = (const float*)d_in[12];
    const float* be2  = (const float*)d_in[13];
    float* ws  = (float*)d_ws;
    float* out = (float*)d_out;

    k1_sums     <<<dim3(576), dim3(256), 0, stream>>>(node, Wvs, ws);
    k2_t_s      <<<dim3(33),  dim3(512), 0, stream>>>(Wo, ws);
    k4_ln1_ffn1 <<<dim3(32),  dim3(256), 0, stream>>>(g1, be1, W1, ws);
    k5_ffn2     <<<dim3(32),  dim3(512), 0, stream>>>(b1, W2, ws);
    k6_ln2_bcast<<<dim3(512), dim3(256), 0, stream>>>(b2, g2, be2, ws, out);
}

// Round 3
// 23.482 us; speedup vs baseline: 2.1197x; 1.0345x over previous
//
#include <hip/hip_runtime.h>

#define NN   4096
#define IND  512
#define REPR 512
#define NH   8
#define KD   64
#define HID  2048
#define LN_EPS 1e-5f

// ws float offsets (16B-aligned)
#define OFF_NP   0        // 512          node partial sums
#define OFF_CVP  512      // 64*64=4096   cv partials (8 heads x 8 k-chunks x 64)
#define OFF_S    4608     // 1 (pad 16)   grand sum of node_matrix
#define OFF_T    4624     // 512          final t vector
#define OFF_H    5136     // 2048         final FFN1 hidden (post-relu)
#define OFF_YP   7184     // 32*512       FFN2 partials
// end 23568 floats ~ 94 KB

__device__ inline float wave_reduce(float v) {
    #pragma unroll
    for (int o = 32; o > 0; o >>= 1) v += __shfl_xor(v, o);
    return v;
}

__device__ inline float block_reduce_512(float v, float* sred, int t) {
    v = wave_reduce(v);
    if ((t & 63) == 0) sred[t >> 6] = v;
    __syncthreads();
    float r = 0.f;
    #pragma unroll
    for (int i = 0; i < 8; ++i) r += sred[i];
    __syncthreads();
    return r;
}

__device__ inline float block_reduce_256(float v, float* sred, int t) {
    v = wave_reduce(v);
    if ((t & 63) == 0) sred[t >> 6] = v;
    __syncthreads();
    float r = sred[0] + sred[1] + sred[2] + sred[3];
    __syncthreads();
    return r;
}

// K1: blocks 0..511 -> node partial sums; blocks 512..575 -> cv partials
__global__ void k1_sums(const float* __restrict__ node, const float* __restrict__ Wvs,
                        float* __restrict__ ws) {
    const int bid = blockIdx.x, t = threadIdx.x;  // 256 threads
    __shared__ float sred[8];
    __shared__ float sm[256];
    if (bid < 512) {
        const float4* n4 = (const float4*)node;
        const int base = bid * 1024;
        float acc = 0.f;
        #pragma unroll
        for (int i = 0; i < 4; ++i) {
            float4 v = n4[base + i * 256 + t];
            acc += (v.x + v.y) + (v.z + v.w);
        }
        acc = wave_reduce(acc);
        if ((t & 63) == 0) sred[t >> 6] = acc;
        __syncthreads();
        if (t == 0) ws[OFF_NP + bid] = sred[0] + sred[1] + sred[2] + sred[3];
    } else {
        const int b = bid - 512;            // 0..63
        const int h = b >> 3, c = b & 7;    // head, 64-wide k-chunk
        const int n = t & 63, ks = t >> 6;  // ks 0..3
        const float* w = Wvs + h * (IND * KD);
        float acc = 0.f;
        #pragma unroll
        for (int q = 0; q < 16; ++q) {
            const int k = c * 64 + ks + q * 4;
            acc += w[k * KD + n];
        }
        sm[t] = acc;
        __syncthreads();
        if (ks == 0)
            ws[OFF_CVP + b * 64 + n] = sm[n] + sm[64 + n] + sm[128 + n] + sm[192 + n];
    }
}

// K2: blocks 0..15 -> final t (32-n column slice of Wo, full 512-row sum);
//     block 16 -> finalize S.  512 threads.
__global__ void k2_t_s(const float* __restrict__ Wo, float* __restrict__ ws) {
    const int bid = blockIdx.x, t = threadIdx.x;
    __shared__ float cvs[512];
    __shared__ float sm[512];
    __shared__ float sred[8];
    if (bid < 16) {
        // finalize cv: cvs[r], r = h*64+m
        {
            float a = 0.f;
            const int hh = t >> 6, mm = t & 63;
            #pragma unroll
            for (int c = 0; c < 8; ++c) a += ws[OFF_CVP + (hh * 8 + c) * 64 + mm];
            cvs[t] = a;
        }
        __syncthreads();
        const int r0 = t >> 5, nl = t & 31;       // 16 row-groups, 32 cols
        const int n = bid * 32 + nl;
        float acc = 0.f;
        #pragma unroll
        for (int i = 0; i < 32; ++i) {
            const int r = r0 + 16 * i;
            acc += cvs[r] * Wo[r * REPR + n];     // 128B per row-slice
        }
        sm[t] = acc;
        __syncthreads();
        if (t < 32) {
            float s = 0.f;
            #pragma unroll
            for (int g = 0; g < 16; ++g) s += sm[g * 32 + t];
            ws[OFF_T + bid * 32 + t] = s;
        }
    } else {
        float v = wave_reduce(ws[OFF_NP + t]);
        if ((t & 63) == 0) sred[t >> 6] = v;
        __syncthreads();
        if (t == 0) {
            float s = 0.f;
            #pragma unroll
            for (int i = 0; i < 8; ++i) s += sred[i];
            ws[OFF_S] = s;
        }
    }
}

// K3: redundant LN1 per block (from final t + S), then FFN1 final for a 32-j chunk.
// 64 blocks x 512 threads.
__global__ void k3_ln1_ffn1(const float* __restrict__ g1, const float* __restrict__ be1,
                            const float* __restrict__ W1, const float* __restrict__ b1,
                            float* __restrict__ ws) {
    const int bid = blockIdx.x, t = threadIdx.x;
    __shared__ float xs[REPR];
    __shared__ float sm[512];
    __shared__ float sred[8];
    const float S = ws[OFF_S];
    const float r = S * ws[OFF_T + t];            // this thread owns n = t
    const float tot = block_reduce_512(r, sred, t);
    const float mu = tot * (1.f / REPR);
    const float d = r - mu;
    const float var = block_reduce_512(d * d, sred, t);
    const float inv = rsqrtf(var * (1.f / REPR) + LN_EPS);
    xs[t] = d * inv * g1[t] + be1[t];
    __syncthreads();
    // FFN1: j = bid*32 + jl, sum over all 512 n (16 groups x 32 strided)
    const int n0 = t >> 5, jl = t & 31;
    const int j = bid * 32 + jl;
    float acc = 0.f;
    #pragma unroll
    for (int i = 0; i < 32; ++i) {
        const int n = n0 + 16 * i;
        acc += xs[n] * W1[n * HID + j];           // 128B per row-slice
    }
    sm[t] = acc;
    __syncthreads();
    if (t < 32) {
        float s = 0.f;
        #pragma unroll
        for (int g = 0; g < 16; ++g) s += sm[g * 32 + t];
        const float v = s + b1[bid * 32 + t];
        ws[OFF_H + bid * 32 + t] = v > 0.f ? v : 0.f;
    }
}

// K4: FFN2 partials. 32 blocks x 512 threads; block b owns j-range [b*64, b*64+64).
__global__ void k4_ffn2(const float* __restrict__ W2, float* __restrict__ ws) {
    const int bid = blockIdx.x, t = threadIdx.x;
    __shared__ float hs[64];
    __shared__ float4 part[512];
    if (t < 64) hs[t] = ws[OFF_H + bid * 64 + t];
    __syncthreads();
    const int n4 = t & 127, jg = t >> 7;          // float4 col, 4 j-groups of 16
    const float4* W24 = (const float4*)W2;        // row j = 128 float4
    float4 acc = make_float4(0.f, 0.f, 0.f, 0.f);
    #pragma unroll
    for (int i = 0; i < 16; ++i) {
        const int jl = jg * 16 + i;
        const float hv = hs[jl];
        const float4 w = W24[(bid * 64 + jl) * 128 + n4];
        acc.x += hv * w.x; acc.y += hv * w.y; acc.z += hv * w.z; acc.w += hv * w.w;
    }
    part[t] = acc;
    __syncthreads();
    if (t < 128) {
        const float4 a = part[t], b = part[128 + t], c = part[256 + t], d = part[384 + t];
        ((float4*)(ws + OFF_YP))[bid * 128 + t] =
            make_float4(a.x + b.x + c.x + d.x, a.y + b.y + c.y + d.y,
                        a.z + b.z + c.z + d.z, a.w + b.w + c.w + d.w);
    }
}

// K5: redundant (yp combine + b2 + LN2) per block, then write 32 output rows.
// 128 blocks x 256 threads.
__global__ void k5_ln2_bcast(const float* __restrict__ b2, const float* __restrict__ g2,
                             const float* __restrict__ be2, const float* __restrict__ ws,
                             float* __restrict__ out) {
    const int bid = blockIdx.x, t = threadIdx.x;
    __shared__ float row[REPR];
    __shared__ float sred[4];
    if (t < 128) {
        const float4* yp4 = (const float4*)(ws + OFF_YP);
        float4 a = ((const float4*)b2)[t];
        #pragma unroll
        for (int p = 0; p < 32; ++p) {
            const float4 v = yp4[p * 128 + t];
            a.x += v.x; a.y += v.y; a.z += v.z; a.w += v.w;
        }
        ((float4*)row)[t] = a;
    }
    __syncthreads();
    const float v0 = row[t], v1 = row[t + 256];
    const float tot = block_reduce_256(v0 + v1, sred, t);
    const float mu = tot * (1.f / REPR);
    const float d0 = v0 - mu, d1 = v1 - mu;
    const float var = block_reduce_256(d0 * d0 + d1 * d1, sred, t);
    const float inv = rsqrtf(var * (1.f / REPR) + LN_EPS);
    __syncthreads();
    row[t]       = d0 * inv * g2[t] + be2[t];
    row[t + 256] = d1 * inv * g2[t + 256] + be2[t + 256];
    __syncthreads();
    const float4* r4 = (const float4*)row;        // 128 float4
    float4* o4 = (float4*)out + bid * 4096;       // 32 rows per block
    #pragma unroll
    for (int i = 0; i < 16; ++i) {
        const int idx = i * 256 + t;
        o4[idx] = r4[idx & 127];
    }
}

extern "C" void kernel_launch(void* const* d_in, const int* in_sizes, int n_in,
                              void* d_out, int out_size, void* d_ws, size_t ws_size,
                              hipStream_t stream) {
    const float* node = (const float*)d_in[0];
    // d_in[1] adjacency, d_in[2] Wks, d_in[3] Wqs — analytically unused
    const float* Wvs  = (const float*)d_in[4];
    const float* Wo   = (const float*)d_in[5];
    const float* W1   = (const float*)d_in[6];
    const float* b1   = (const float*)d_in[7];
    const float* W2   = (const float*)d_in[8];
    const float* b2   = (const float*)d_in[9];
    const float* g1   = (const float*)d_in[10];
    const float* be1  = (const float*)d_in[11];
    const float* g2   = (const float*)d_in[12];
    const float* be2  = (const float*)d_in[13];
    float* ws  = (float*)d_ws;
    float* out = (float*)d_out;

    k1_sums     <<<dim3(576), dim3(256), 0, stream>>>(node, Wvs, ws);
    k2_t_s      <<<dim3(17),  dim3(512), 0, stream>>>(Wo, ws);
    k3_ln1_ffn1 <<<dim3(64),  dim3(512), 0, stream>>>(g1, be1, W1, b1, ws);
    k4_ffn2     <<<dim3(32),  dim3(512), 0, stream>>>(W2, ws);
    k5_ln2_bcast<<<dim3(128), dim3(256), 0, stream>>>(b2, g2, be2, ws, out);
}